// Round 3
// baseline (2983.199 us; speedup 1.0000x reference)
//
#include <hip/hip_runtime.h>
#include <stdint.h>

// UniLSTM: B=64, T=512, E=1024, H=1024.
// Phase 0: f32->f16 converts + bias sum.
// Phase 1: xprojT[T][64][4096] = (x @ W_ih^T + bsum), f16, time-major layout.
// Phase 2: persistent recurrence, 128 WGs x 512 thr = 4 batch-groups x 32 unit-slices.
//          h exchanged as TAGGED u32 words ((t+1)<<16 | h_f16) in ping-pong LLC
//          buffers; consumers poll the data itself (tag==t) -> ONE round trip
//          per step, no flags, no store-ack drain (R2 lesson).

typedef _Float16 half8 __attribute__((ext_vector_type(8)));
typedef _Float16 half4_ __attribute__((ext_vector_type(4)));
typedef float f32x4 __attribute__((ext_vector_type(4)));
typedef unsigned int u32x4 __attribute__((ext_vector_type(4)));

#define T_SEQ 512

// ---------------- converts ----------------
__global__ void k_f32_to_f16(const float* __restrict__ s, _Float16* __restrict__ d, int n4) {
  int i = blockIdx.x * blockDim.x + threadIdx.x;
  if (i >= n4) return;
  f32x4 v = ((const f32x4*)s)[i];
  half4_ h;
  h.x = (_Float16)v.x; h.y = (_Float16)v.y; h.z = (_Float16)v.z; h.w = (_Float16)v.w;
  ((half4_*)d)[i] = h;
}

__global__ void k_bias_sum(const float* __restrict__ a, const float* __restrict__ b,
                           float* __restrict__ o) {
  int i = blockIdx.x * blockDim.x + threadIdx.x;
  if (i < 4096) o[i] = a[i] + b[i];
}

// ---------------- phase 1: input projection GEMM ----------------
// logical C[M=32768, N=4096] = X[M,1024] @ W[N,1024]^T + bsum[N], stored TIME-MAJOR:
// row = b*512+t  ->  written at C[(t*64 + b)*4096 + col]
__global__ __launch_bounds__(256, 2) void k_gemm_xproj(
    const _Float16* __restrict__ X, const _Float16* __restrict__ W,
    const float* __restrict__ bsum, _Float16* __restrict__ C) {
  __shared__ _Float16 As[128 * 64];
  __shared__ _Float16 Bs[128 * 64];
  const int bid = blockIdx.x;
  const int ntile = bid & 31, mtile = bid >> 5;
  const int tid = threadIdx.x;
  const int wave = tid >> 6, lane = tid & 63;
  const int wr = wave >> 1, wc = wave & 1;
  const int R0 = lane >> 3, cg = lane & 7;

  f32x4 acc[4][4];
#pragma unroll
  for (int m = 0; m < 4; m++)
#pragma unroll
    for (int n = 0; n < 4; n++) acc[m][n] = (f32x4){0.f, 0.f, 0.f, 0.f};

  for (int k0 = 0; k0 < 1024; k0 += 64) {
#pragma unroll
    for (int i = 0; i < 4; i++) {
      const int rr = (wave * 4 + i) * 8 + R0;
      const _Float16* ga = X + (size_t)(mtile * 128 + rr) * 1024 + k0 + ((cg ^ (rr & 7)) * 8);
      const _Float16* gb = W + (size_t)(ntile * 128 + rr) * 1024 + k0 + ((cg ^ (rr & 7)) * 8);
      __builtin_amdgcn_global_load_lds(
          (const __attribute__((address_space(1))) void*)ga,
          (__attribute__((address_space(3))) void*)((char*)As + (wave * 4 + i) * 1024), 16, 0, 0);
      __builtin_amdgcn_global_load_lds(
          (const __attribute__((address_space(1))) void*)gb,
          (__attribute__((address_space(3))) void*)((char*)Bs + (wave * 4 + i) * 1024), 16, 0, 0);
    }
    asm volatile("s_waitcnt vmcnt(0)" ::: "memory");
    __syncthreads();
#pragma unroll
    for (int kk = 0; kk < 2; kk++) {
      half8 af[4], bf[4];
#pragma unroll
      for (int m = 0; m < 4; m++) {
        int r = wr * 64 + m * 16 + (lane & 15);
        af[m] = *(const half8*)((const char*)As + r * 128 +
                                (((kk * 4 + (lane >> 4)) ^ (r & 7)) << 4));
      }
#pragma unroll
      for (int n = 0; n < 4; n++) {
        int r = wc * 64 + n * 16 + (lane & 15);
        bf[n] = *(const half8*)((const char*)Bs + r * 128 +
                                (((kk * 4 + (lane >> 4)) ^ (r & 7)) << 4));
      }
#pragma unroll
      for (int m = 0; m < 4; m++)
#pragma unroll
        for (int n = 0; n < 4; n++)
          acc[m][n] = __builtin_amdgcn_mfma_f32_16x16x32_f16(af[m], bf[n], acc[m][n], 0, 0, 0);
    }
    __syncthreads();
  }
#pragma unroll
  for (int n = 0; n < 4; n++) {
    int col = ntile * 128 + wc * 64 + n * 16 + (lane & 15);
    float bs = bsum[col];
#pragma unroll
    for (int m = 0; m < 4; m++)
#pragma unroll
      for (int q = 0; q < 4; q++) {
        int row = mtile * 128 + wr * 64 + m * 16 + (lane >> 4) * 4 + q;  // = b*512 + t
        int bb = row >> 9, tt = row & 511;
        C[((size_t)tt * 64 + bb) * 4096 + col] = (_Float16)(acc[m][n][q] + bs);
      }
  }
}

// ---------------- phase 2: recurrence ----------------
// 128 WGs x 512 thr. WG = (group g = wg>>5 [16 batch rows], slice s2 = wg&31 [32 units]).
// wave w: gate G = w>>1, unit-half uh = w&1 -> 16 W_hh rows 1024*G + s2*32 + uh*16 ...
// Tagged ping-pong exchange: store buf[(t+1)&1], poll buf[t&1] until all tags==t.
__global__ __launch_bounds__(512, 2) void k_lstm_rec(
    const _Float16* __restrict__ Whh,     // [4096][1024] f16
    const _Float16* __restrict__ xprojT,  // [512][64][4096] f16 (time-major)
    const int* __restrict__ seqlen,       // [64]
    unsigned* __restrict__ hbuf,          // [2][64][1024] tagged u32, tags zeroed/launch
    float* __restrict__ out) {            // [64][1024] f32
  __shared__ _Float16 h_lds[16 * 1024];  // 32 KB, XOR-swizzled 16B chunks
  __shared__ float gates[16 * 132];      // padded stride 132 (bank-conflict-free)

  const int wg = blockIdx.x;
  const int g = wg >> 5, s2 = wg & 31;
  const int tid = threadIdx.x;
  const int wave = tid >> 6, lane = tid & 63;
  const int G = wave >> 1, uh = wave & 1;

  for (int i = tid; i < 4096; i += 512) ((uint64_t*)h_lds)[i] = 0ull;  // h_0 = 0

  // W_hh B-fragments, register-resident: col n=lane&15 -> W row 1024*G + s2*32 + uh*16 + n
  half8 wfrag[32];
  {
    const _Float16* wrow =
        Whh + (size_t)(1024 * G + s2 * 32 + uh * 16 + (lane & 15)) * 1024 + (lane >> 4) * 8;
#pragma unroll
    for (int kk = 0; kk < 32; kk++) wfrag[kk] = *(const half8*)(wrow + kk * 32);
  }

  int Lg = 1;
  for (int b = 0; b < 16; b++) {
    int L = seqlen[g * 16 + b];
    Lg = L > Lg ? L : Lg;
  }
  const int be = tid >> 5, ue = tid & 31;  // elementwise cell (batch row, unit in slice)
  const int mylen = seqlen[g * 16 + be];
  float c_state = 0.f;

  const int bA = lane & 15;        // A-frag batch row
  const int rowbase = bA * 2048;   // byte base in h_lds
  const int xorm = (bA & 7) << 4;  // XOR swizzle (bytes)
  const int pb = tid >> 5;         // poll: row 0..15
  const int pj = tid & 31;         // poll: chunk seed; chunks j = pj + 32*i

  __syncthreads();

  for (int t = 0; t < Lg; t++) {
    // xp for this step (independent of h) — issued before the poll, latency hidden
    float xp[4];
#pragma unroll
    for (int q = 0; q < 4; q++) {
      int bm = (lane >> 4) * 4 + q;
      xp[q] = (float)xprojT[((size_t)t * 64 + g * 16 + bm) * 4096 + 1024 * G + s2 * 32 +
                            uh * 16 + (lane & 15)];
    }
    if (t > 0) {
      const unsigned* src = hbuf + ((size_t)(t & 1)) * 65536 + (size_t)(g * 16 + pb) * 1024;
      u32x4 pv[8];
      for (;;) {
#pragma unroll
        for (int i = 0; i < 4; i++) {
          asm volatile("global_load_dwordx4 %0, %1, off sc0 sc1"
                       : "=v"(pv[2 * i]) : "v"(src + (pj + 32 * i) * 8) : "memory");
          asm volatile("global_load_dwordx4 %0, %1, off sc0 sc1"
                       : "=v"(pv[2 * i + 1]) : "v"(src + (pj + 32 * i) * 8 + 4) : "memory");
        }
        asm volatile("s_waitcnt vmcnt(0)" ::: "memory");
        bool ok = true;
#pragma unroll
        for (int i = 0; i < 8; i++)
#pragma unroll
          for (int d = 0; d < 4; d++) ok &= ((pv[i][d] >> 16) == (unsigned)t);
        if (__all(ok)) break;
      }
      // strip tags, pack pairs -> f16x8 chunks, write swizzled LDS (chunk-interleaved)
#pragma unroll
      for (int i = 0; i < 4; i++) {
        u32x4 pk;
        pk.x = (pv[2 * i].x & 0xffffu) | (pv[2 * i].y << 16);
        pk.y = (pv[2 * i].z & 0xffffu) | (pv[2 * i].w << 16);
        pk.z = (pv[2 * i + 1].x & 0xffffu) | (pv[2 * i + 1].y << 16);
        pk.w = (pv[2 * i + 1].z & 0xffffu) | (pv[2 * i + 1].w << 16);
        int j = pj + 32 * i;
        *(u32x4*)((char*)h_lds + pb * 2048 + ((j ^ (pb & 7)) << 4)) = pk;
      }
    }
    __syncthreads();  // (A) h_lds ready

    // gates: M=16 batch x N=16 cols per wave, K=1024 -> 32 MFMAs, 2 accumulators
    f32x4 acc0 = (f32x4){0.f, 0.f, 0.f, 0.f};
    f32x4 acc1 = (f32x4){0.f, 0.f, 0.f, 0.f};
#pragma unroll
    for (int kk = 0; kk < 32; kk += 2) {
      half8 a0 = *(const half8*)((const char*)h_lds + rowbase +
                                 ((((kk + 0) * 4 + (lane >> 4)) << 4) ^ xorm));
      half8 a1 = *(const half8*)((const char*)h_lds + rowbase +
                                 ((((kk + 1) * 4 + (lane >> 4)) << 4) ^ xorm));
      acc0 = __builtin_amdgcn_mfma_f32_16x16x32_f16(a0, wfrag[kk], acc0, 0, 0, 0);
      acc1 = __builtin_amdgcn_mfma_f32_16x16x32_f16(a1, wfrag[kk + 1], acc1, 0, 0, 0);
    }
#pragma unroll
    for (int q = 0; q < 4; q++) {
      int bm = (lane >> 4) * 4 + q;
      gates[bm * 132 + wave * 16 + (lane & 15)] = (acc0[q] + acc1[q]) + xp[q];
    }
    __syncthreads();  // (B) gates ready

    // elementwise: thread owns cell (be, ue); gates col = G*32 + ue
    float iv = gates[be * 132 + ue];
    float fv = gates[be * 132 + 32 + ue];
    float gv = gates[be * 132 + 64 + ue];
    float ov = gates[be * 132 + 96 + ue];
    iv = 1.f / (1.f + __expf(-iv));
    fv = 1.f / (1.f + __expf(-fv));
    gv = 1.f - 2.f / (1.f + __expf(2.f * gv));
    ov = 1.f / (1.f + __expf(-ov));
    c_state = fv * c_state + iv * gv;
    float tc = 1.f - 2.f / (1.f + __expf(2.f * c_state));
    float hv = ov * tc;
    if (t + 1 == mylen) out[(size_t)(g * 16 + be) * 1024 + s2 * 32 + ue] = hv;

    _Float16 hf = (_Float16)hv;
    unsigned short hb16;
    __builtin_memcpy(&hb16, &hf, 2);
    unsigned tagword = ((unsigned)(t + 1) << 16) | (unsigned)hb16;
    __hip_atomic_store(hbuf + ((size_t)((t + 1) & 1)) * 65536 + (size_t)(g * 16 + be) * 1024 +
                           s2 * 32 + ue,
                       tagword, __ATOMIC_RELAXED, __HIP_MEMORY_SCOPE_AGENT);
    // no drain, no flag, no barrier — tag travels with the data
  }
}

// ---------------- launch ----------------
extern "C" void kernel_launch(void* const* d_in, const int* in_sizes, int n_in, void* d_out,
                              int out_size, void* d_ws, size_t ws_size, hipStream_t stream) {
  const float* emb = (const float*)d_in[0];   // [64,512,1024]
  const int* slen = (const int*)d_in[1];      // [64]
  const float* Wih = (const float*)d_in[2];   // [4096,1024]
  const float* Whh = (const float*)d_in[3];   // [4096,1024]
  const float* bih = (const float*)d_in[4];   // [4096]
  const float* bhh = (const float*)d_in[5];   // [4096]
  float* out = (float*)d_out;

  char* ws = (char*)d_ws;
  _Float16* xprojT = (_Float16*)(ws + 0);        // 268,435,456 B [512][64][4096]
  _Float16* xf = (_Float16*)(ws + 268435456);    //  67,108,864 B (dead after GEMM)
  _Float16* wihf = (_Float16*)(ws + 335544320);  //   8,388,608 B
  _Float16* whhf = (_Float16*)(ws + 343932928);  //   8,388,608 B
  float* bsum = (float*)(ws + 352321536);        //      16,384 B
  // rec-phase tagged h ping-pong aliases the dead xf region:
  unsigned* hbuf = (unsigned*)(ws + 268435456);  //     524,288 B [2][64][1024] u32

  k_f32_to_f16<<<(8388608 + 255) / 256, 256, 0, stream>>>(emb, xf, 8388608);
  k_f32_to_f16<<<(1048576 + 255) / 256, 256, 0, stream>>>(Wih, wihf, 1048576);
  k_f32_to_f16<<<(1048576 + 255) / 256, 256, 0, stream>>>(Whh, whhf, 1048576);
  k_bias_sum<<<16, 256, 0, stream>>>(bih, bhh, bsum);
  k_gemm_xproj<<<8192, 256, 0, stream>>>(xf, wihf, bsum, xprojT);
  // zero the tag words AFTER the GEMM consumed xf (hbuf aliases xf)
  hipMemsetAsync(hbuf, 0, 524288, stream);
  k_lstm_rec<<<128, 512, 0, stream>>>(whhf, xprojT, slen, hbuf, out);
}